// Round 2
// baseline (1735.278 us; speedup 1.0000x reference)
//
#include <hip/hip_runtime.h>
#include <cstdint>

typedef unsigned short u16;
typedef __attribute__((ext_vector_type(4))) float f32x4;
typedef __attribute__((ext_vector_type(8))) short bf16x8;   // 8 bf16 in 4 VGPRs
typedef __attribute__((ext_vector_type(4))) u16 u16x4;

constexpr int NB = 1024;   // batch
constexpr int NT = 200;    // time
constexpr int ND = 128;    // input dim
constexpr int NU = 128;    // units
constexpr int NG = 512;    // 4*U gates
constexpr int ROWS = 16;   // batch rows per block (MFMA M)
constexpr int AK = 512;    // A-tile k extent: [xhi|xlo|hhi|hlo] x 128
constexpr int LDS_A_ELEMS  = ROWS * AK;   // 8192 u16 = 16 KiB
constexpr int LDS_WK_ELEMS = NG * ND;     // 65536 u16 = 128 KiB (Wk_lo, [col][k])

__device__ __forceinline__ u16 f2bf(float x) {
    uint32_t u = __builtin_bit_cast(uint32_t, x);
    u = (u + 0x7fffu + ((u >> 16) & 1u)) >> 16;   // RNE
    return (u16)u;
}
__device__ __forceinline__ float bf2f(u16 b) {
    uint32_t u = ((uint32_t)b) << 16;
    return __builtin_bit_cast(float, u);
}
__device__ __forceinline__ float sigm(float x) {
    return __builtin_amdgcn_rcpf(1.f + __expf(-x));
}
__device__ __forceinline__ float tanh_fast(float x) {
    float e = __expf(-2.f * fabsf(x));
    float t = (1.f - e) * __builtin_amdgcn_rcpf(1.f + e);
    return copysignf(t, x);
}

// ---- fused 2-layer LSTM scan, one direction per blockIdx.y ------------------
// Split-precision everywhere: A-operands (x_t and h) as bf16 hi+lo pairs,
// Wr as hi (VGPR) + lo (VGPR), Wk as hi (VGPR) + lo (LDS). All matmuls are
// exact to ~eps_bf16^2; recurrent state c and feedback h effectively fp32.
__global__ __launch_bounds__(512, 2)
void lstm_scan(const float* __restrict__ x,
               const float* __restrict__ fwk, const float* __restrict__ fwrk,
               const float* __restrict__ fwb,
               const float* __restrict__ bwk, const float* __restrict__ bwrk,
               const float* __restrict__ bwb,
               float* __restrict__ buf_fw, float* __restrict__ buf_bw) {
    extern __shared__ __align__(16) u16 smem[];
    u16* A    = smem;                 // [16][512] bf16, XOR-swizzled rows
    u16* WKLO = smem + LDS_A_ELEMS;   // [512 col][128 k] bf16, XOR-swizzled

    const int tid  = threadIdx.x;
    const int lane = tid & 63;
    const int wv   = tid >> 6;          // wave 0..7
    const int dir  = blockIdx.y;        // 0 = fw, 1 = bw
    const int base_b = blockIdx.x * ROWS;

    const float* kp = dir ? bwk  : fwk;
    const float* rp = dir ? bwrk : fwrk;
    const float* bp = dir ? bwb  : fwb;
    float* buf = dir ? buf_bw : buf_fw;

    const int q  = lane >> 4;           // k-group 0..3
    const int cl = lane & 15;           // A-row / B-col within tile
    const int uu = (wv << 4) + cl;      // unit 0..127 owned by this lane

    const int sr = tid >> 5;            // staging row 0..15
    const int sc = (tid & 31) << 2;     // staging col 0..124

    for (int layer = 0; layer < 2; ++layer) {
        const float* Wk = kp + layer * ND * NG;   // [128][512]
        const float* Wr = rp + layer * NU * NG;   // [128][512]
        const float* Bv = bp + layer * NG;
        const float* src = layer ? buf : x;       // fp32 [B][T][128]

        // ---- resident weight fragments (B-side): Wk_hi, Wr_hi, Wr_lo
        bf16x8 wkh[4][4], wrh[4][4], wrl[4][4];
        #pragma unroll
        for (int g = 0; g < 4; ++g) {
            const int col = g * NU + uu;
            #pragma unroll
            for (int s = 0; s < 4; ++s) {
                bf16x8 fa, fh, fl;
                #pragma unroll
                for (int j = 0; j < 8; ++j) {
                    const int k = s * 32 + q * 8 + j;
                    fa[j] = (short)f2bf(Wk[k * NG + col]);
                    const float w = Wr[k * NG + col];
                    const u16 hi = f2bf(w);
                    fh[j] = (short)hi;
                    fl[j] = (short)f2bf(w - bf2f(hi));
                }
                wkh[g][s] = fa; wrh[g][s] = fh; wrl[g][s] = fl;
            }
        }
        float bias[4];
        #pragma unroll
        for (int g = 0; g < 4; ++g) bias[g] = Bv[g * NU + uu];

        __syncthreads();   // previous layer completely done with LDS + buf

        // ---- fill Wk_lo into LDS (transposed [col][k], swizzled), zero A
        for (int idx = tid; idx < LDS_WK_ELEMS; idx += 512) {
            const int col = idx & (NG - 1);
            const int k   = idx >> 9;
            const float w = Wk[k * NG + col];
            const float lo = w - bf2f(f2bf(w));
            WKLO[(uint32_t)(col * 256 + ((2 * k) ^ ((col & 7) << 4))) >> 1] = f2bf(lo);
        }
        for (int i = tid; i < LDS_A_ELEMS; i += 512) A[i] = 0;
        f32x4 cc = {0.f, 0.f, 0.f, 0.f};
        __syncthreads();

        for (int step = 0; step < NT; ++step) {
            const int t = dir ? (NT - 1 - step) : step;

            // stage x_t as hi+lo into A's k<256 half
            {
                const float4 v = *(const float4*)
                    &src[(size_t)(base_b + sr) * (NT * NU) + (size_t)t * NU + sc];
                const float vv[4] = {v.x, v.y, v.z, v.w};
                u16x4 hi4, lo4;
                #pragma unroll
                for (int e = 0; e < 4; ++e) {
                    const u16 h = f2bf(vv[e]);
                    hi4[e] = h;
                    lo4[e] = f2bf(vv[e] - bf2f(h));
                }
                const uint32_t b0 = (uint32_t)(sr * 1024 + ((2 * sc) ^ ((sr & 7) << 4)));
                *(u16x4*)&A[(b0 >> 1)]       = hi4;   // x_hi: k in [0,128)
                *(u16x4*)&A[(b0 >> 1) + 128] = lo4;   // x_lo: k in [128,256)
            }
            __syncthreads();

            f32x4 acc[4];
            #pragma unroll
            for (int g = 0; g < 4; ++g)
                acc[g] = (f32x4){bias[g], bias[g], bias[g], bias[g]};

            #pragma unroll
            for (int s = 0; s < 4; ++s) {
                const uint32_t ab =
                    (uint32_t)(cl * 1024 + ((s * 64 + q * 16) ^ ((cl & 7) << 4)));
                const bf16x8 axh = *(const bf16x8*)&A[(ab >> 1)];
                const bf16x8 axl = *(const bf16x8*)&A[(ab >> 1) + 128];
                const bf16x8 ahh = *(const bf16x8*)&A[(ab >> 1) + 256];
                const bf16x8 ahl = *(const bf16x8*)&A[(ab >> 1) + 384];
                #pragma unroll
                for (int g = 0; g < 4; ++g) {
                    const int col = g * NU + uu;
                    const bf16x8 wkl = *(const bf16x8*)
                        &WKLO[(uint32_t)(col * 256 + ((s * 64 + q * 16) ^ ((cl & 7) << 4))) >> 1];
                    acc[g] = __builtin_amdgcn_mfma_f32_16x16x32_bf16(axh, wkh[g][s], acc[g], 0, 0, 0);
                    acc[g] = __builtin_amdgcn_mfma_f32_16x16x32_bf16(axl, wkh[g][s], acc[g], 0, 0, 0);
                    acc[g] = __builtin_amdgcn_mfma_f32_16x16x32_bf16(axh, wkl,       acc[g], 0, 0, 0);
                    acc[g] = __builtin_amdgcn_mfma_f32_16x16x32_bf16(ahh, wrh[g][s], acc[g], 0, 0, 0);
                    acc[g] = __builtin_amdgcn_mfma_f32_16x16x32_bf16(ahl, wrh[g][s], acc[g], 0, 0, 0);
                    acc[g] = __builtin_amdgcn_mfma_f32_16x16x32_bf16(ahh, wrl[g][s], acc[g], 0, 0, 0);
                }
            }
            __syncthreads();   // frag reads done before h region is overwritten

            // gates + state; C/D layout: col = lane&15 (unit), row = q*4+j (batch row)
            #pragma unroll
            for (int j = 0; j < 4; ++j) {
                const int r = q * 4 + j;
                const float gi = sigm(acc[0][j]);
                const float gf = sigm(acc[1][j]);
                const float gg = tanh_fast(acc[2][j]);
                const float go = sigm(acc[3][j]);
                const float cn = gf * cc[j] + gi * gg;
                cc[j] = cn;
                const float h = go * tanh_fast(cn);
                const u16 hh = f2bf(h);
                const u16 hl = f2bf(h - bf2f(hh));
                const uint32_t hb = (uint32_t)(r * 1024 + ((2 * uu) ^ ((r & 7) << 4)));
                A[(hb >> 1) + 256] = hh;   // h_hi: k in [256,384)
                A[(hb >> 1) + 384] = hl;   // h_lo: k in [384,512)
                buf[(size_t)(base_b + r) * (NT * NU) + (size_t)t * NU + uu] = h;
            }
            // next step's post-staging barrier orders these h writes vs reads
        }
    }
}

// ---- merge: out = 0.5*(fw + bw) ---------------------------------------------
__global__ void merge_out(const float* __restrict__ a, const float* __restrict__ b,
                          float* __restrict__ o, int nvec) {
    int i = blockIdx.x * blockDim.x + threadIdx.x;
    const int st = gridDim.x * blockDim.x;
    for (; i < nvec; i += st) {
        const float4 va = ((const float4*)a)[i];
        const float4 vb = ((const float4*)b)[i];
        float4 r;
        r.x = 0.5f * (va.x + vb.x);
        r.y = 0.5f * (va.y + vb.y);
        r.z = 0.5f * (va.z + vb.z);
        r.w = 0.5f * (va.w + vb.w);
        ((float4*)o)[i] = r;
    }
}

extern "C" void kernel_launch(void* const* d_in, const int* in_sizes, int n_in,
                              void* d_out, int out_size, void* d_ws, size_t ws_size,
                              hipStream_t stream) {
    const float* x    = (const float*)d_in[0];
    const float* fwk  = (const float*)d_in[1];
    const float* fwrk = (const float*)d_in[2];
    const float* fwb  = (const float*)d_in[3];
    const float* bwk  = (const float*)d_in[4];
    const float* bwrk = (const float*)d_in[5];
    const float* bwb  = (const float*)d_in[6];
    float* out = (float*)d_out;

    const size_t seq = (size_t)NB * NT * NU;     // 26,214,400 elements
    float* buf_fw = (float*)d_ws;                // fw h-sequence fp32 (l0 then l1 in-place)
    float* buf_bw = buf_fw + seq;                // bw h-sequence fp32

    const size_t lds_bytes = (size_t)(LDS_A_ELEMS + LDS_WK_ELEMS) * sizeof(u16); // 147456
    (void)hipFuncSetAttribute((const void*)lstm_scan,
                              hipFuncAttributeMaxDynamicSharedMemorySize,
                              (int)lds_bytes);

    lstm_scan<<<dim3(NB / ROWS, 2), 512, lds_bytes, stream>>>(
        x, fwk, fwrk, fwb, bwk, bwrk, bwb, buf_fw, buf_bw);

    const int nvec = (int)(seq / 4);
    merge_out<<<2048, 256, 0, stream>>>(buf_fw, buf_bw, out, nvec);
}

// Round 3
// 1722.071 us; speedup vs baseline: 1.0077x; 1.0077x over previous
//
#include <hip/hip_runtime.h>
#include <cstdint>

typedef unsigned short u16;
typedef __attribute__((ext_vector_type(4))) float f32x4;
typedef __attribute__((ext_vector_type(8))) short bf16x8;   // 8 bf16 in 4 VGPRs
typedef __attribute__((ext_vector_type(4))) u16 u16x4;

constexpr int NB = 1024;   // batch
constexpr int NT = 200;    // time
constexpr int ND = 128;    // input dim
constexpr int NU = 128;    // units
constexpr int NG = 512;    // 4*U gates
constexpr int ROWS = 16;   // batch rows per block (MFMA M)
constexpr int AK = 512;    // A-tile k extent: [xhi|xlo|hhi|hlo] x 128
constexpr int LDS_A_ELEMS  = ROWS * AK;   // 8192 u16 = 16 KiB
constexpr int LDS_WK_ELEMS = NG * ND;     // 65536 u16 = 128 KiB (Wk_lo, [col][k])

__device__ __forceinline__ u16 f2bf(float x) {
    uint32_t u = __builtin_bit_cast(uint32_t, x);
    u = (u + 0x7fffu + ((u >> 16) & 1u)) >> 16;   // RNE
    return (u16)u;
}
__device__ __forceinline__ float bf2f(u16 b) {
    uint32_t u = ((uint32_t)b) << 16;
    return __builtin_bit_cast(float, u);
}
__device__ __forceinline__ float sigm(float x) {
    return __builtin_amdgcn_rcpf(1.f + __expf(-x));
}
__device__ __forceinline__ float tanh_fast(float x) {
    float e = __expf(-2.f * fabsf(x));
    float t = (1.f - e) * __builtin_amdgcn_rcpf(1.f + e);
    return copysignf(t, x);
}

// One LSTM layer scan for 16 batch rows. WKL: include the x_hi * Wk_lo
// correction (needed when the layer input has a nonzero temporal mean, i.e.
// layer 1 whose input is the previous layer's h sequence; layer 0's input x
// is zero-mean so its weight-rounding error accumulates incoherently).
template<bool WKL>
__device__ __forceinline__ void run_layer(
    const float* __restrict__ Wk, const float* __restrict__ Wr,
    const float* __restrict__ Bv,
    const float* __restrict__ src, float* __restrict__ dst,
    u16* A, u16* WKLO, const int dir, const int base_b,
    const int tid, const int q, const int cl, const int uu,
    const int sr, const int sc)
{
    __syncthreads();   // prior layer done with LDS; its global dst writes visible

    // ---- resident weight fragments (B-side): Wk_hi, Wr_hi, Wr_lo
    bf16x8 wkh[4][4], wrh[4][4], wrl[4][4];
    #pragma unroll
    for (int g = 0; g < 4; ++g) {
        const int col = g * NU + uu;
        #pragma unroll
        for (int s = 0; s < 4; ++s) {
            bf16x8 fa, fh, fl;
            #pragma unroll
            for (int j = 0; j < 8; ++j) {
                const int k = s * 32 + q * 8 + j;
                fa[j] = (short)f2bf(Wk[k * NG + col]);
                const float w = Wr[k * NG + col];
                const u16 hi = f2bf(w);
                fh[j] = (short)hi;
                fl[j] = (short)f2bf(w - bf2f(hi));
            }
            wkh[g][s] = fa; wrh[g][s] = fh; wrl[g][s] = fl;
        }
    }
    float bias[4];
    #pragma unroll
    for (int g = 0; g < 4; ++g) bias[g] = Bv[g * NU + uu];

    if (WKL) {   // fill Wk_lo into LDS (transposed [col][k], swizzled)
        for (int idx = tid; idx < LDS_WK_ELEMS; idx += 512) {
            const int col = idx & (NG - 1);
            const int k   = idx >> 9;
            const float w = Wk[k * NG + col];
            const float lo = w - bf2f(f2bf(w));
            WKLO[(uint32_t)(col * 256 + ((2 * k) ^ ((col & 15) << 4))) >> 1] = f2bf(lo);
        }
    }
    for (int i = tid; i < LDS_A_ELEMS; i += 512) A[i] = 0;   // h region must be 0
    f32x4 cc = {0.f, 0.f, 0.f, 0.f};

    const size_t srow = (size_t)(base_b + sr) * (NT * NU) + sc;
    float4 cur = *(const float4*)&src[srow + (size_t)(dir ? NT - 1 : 0) * NU];

    __syncthreads();   // WKLO fill + A zero complete

    for (int step = 0; step < NT; ++step) {
        const int t = dir ? (NT - 1 - step) : step;

        // ---- stage x_t (held in regs) as hi+lo into A's k<256 half
        {
            const float vv[4] = {cur.x, cur.y, cur.z, cur.w};
            u16x4 hi4, lo4;
            #pragma unroll
            for (int e = 0; e < 4; ++e) {
                const u16 h = f2bf(vv[e]);
                hi4[e] = h;
                lo4[e] = f2bf(vv[e] - bf2f(h));
            }
            const uint32_t b0 = (uint32_t)(sr * 1024 + ((2 * sc) ^ ((sr & 15) << 4)));
            *(u16x4*)&A[(b0 >> 1)]       = hi4;   // x_hi: k in [0,128)
            *(u16x4*)&A[(b0 >> 1) + 128] = lo4;   // x_lo: k in [128,256)
        }
        __syncthreads();

        // ---- prefetch x_{t+1}: latency hides under frag reads + MFMA + gates
        if (step + 1 < NT) {
            const int tn = dir ? (NT - 2 - step) : (step + 1);
            cur = *(const float4*)&src[srow + (size_t)tn * NU];
        }

        f32x4 accx[4], acch[4];   // separate chains: x-side (carries bias), h-side
        #pragma unroll
        for (int g = 0; g < 4; ++g) {
            accx[g] = (f32x4){bias[g], bias[g], bias[g], bias[g]};
            acch[g] = (f32x4){0.f, 0.f, 0.f, 0.f};
        }

        #pragma unroll
        for (int s = 0; s < 4; ++s) {
            const uint32_t ab =
                (uint32_t)(cl * 1024 + ((s * 64 + q * 16) ^ ((cl & 15) << 4)));
            const bf16x8 axh = *(const bf16x8*)&A[(ab >> 1)];
            const bf16x8 axl = *(const bf16x8*)&A[(ab >> 1) + 128];
            const bf16x8 ahh = *(const bf16x8*)&A[(ab >> 1) + 256];
            const bf16x8 ahl = *(const bf16x8*)&A[(ab >> 1) + 384];
            #pragma unroll
            for (int g = 0; g < 4; ++g) {
                accx[g] = __builtin_amdgcn_mfma_f32_16x16x32_bf16(axh, wkh[g][s], accx[g], 0, 0, 0);
                accx[g] = __builtin_amdgcn_mfma_f32_16x16x32_bf16(axl, wkh[g][s], accx[g], 0, 0, 0);
                if (WKL) {
                    const int col = g * NU + uu;
                    const bf16x8 wkl = *(const bf16x8*)
                        &WKLO[(uint32_t)(col * 256 + ((s * 64 + q * 16) ^ ((col & 15) << 4))) >> 1];
                    accx[g] = __builtin_amdgcn_mfma_f32_16x16x32_bf16(axh, wkl, accx[g], 0, 0, 0);
                }
                acch[g] = __builtin_amdgcn_mfma_f32_16x16x32_bf16(ahh, wrh[g][s], acch[g], 0, 0, 0);
                acch[g] = __builtin_amdgcn_mfma_f32_16x16x32_bf16(ahl, wrh[g][s], acch[g], 0, 0, 0);
                acch[g] = __builtin_amdgcn_mfma_f32_16x16x32_bf16(ahh, wrl[g][s], acch[g], 0, 0, 0);
            }
        }
        __syncthreads();   // frag reads done before h region is overwritten

        // gates + state; C/D layout: col = lane&15 (unit), row = q*4+j (batch row)
        #pragma unroll
        for (int j = 0; j < 4; ++j) {
            const int r = q * 4 + j;
            const float gi = sigm(accx[0][j] + acch[0][j]);
            const float gf = sigm(accx[1][j] + acch[1][j]);
            const float gg = tanh_fast(accx[2][j] + acch[2][j]);
            const float go = sigm(accx[3][j] + acch[3][j]);
            const float cn = gf * cc[j] + gi * gg;
            cc[j] = cn;
            const float h = go * tanh_fast(cn);
            const u16 hh = f2bf(h);
            const u16 hl = f2bf(h - bf2f(hh));
            const uint32_t hb = (uint32_t)(r * 1024 + ((2 * uu) ^ ((r & 15) << 4)));
            A[(hb >> 1) + 256] = hh;   // h_hi: k in [256,384)
            A[(hb >> 1) + 384] = hl;   // h_lo: k in [384,512)
            dst[(size_t)(base_b + r) * (NT * NU) + (size_t)t * NU + uu] = h;
        }
        // next step's post-staging barrier orders these h writes vs reads
    }
}

__global__ __launch_bounds__(512, 2)
void lstm_scan(const float* __restrict__ x,
               const float* __restrict__ fwk, const float* __restrict__ fwrk,
               const float* __restrict__ fwb,
               const float* __restrict__ bwk, const float* __restrict__ bwrk,
               const float* __restrict__ bwb,
               float* __restrict__ buf_fw, float* __restrict__ buf_bw) {
    extern __shared__ __align__(16) u16 smem[];
    u16* A    = smem;                 // [16][512] bf16, XOR-swizzled rows
    u16* WKLO = smem + LDS_A_ELEMS;   // [512 col][128 k] bf16, XOR-swizzled

    const int tid  = threadIdx.x;
    const int lane = tid & 63;
    const int wv   = tid >> 6;          // wave 0..7
    const int dir  = blockIdx.y;        // 0 = fw, 1 = bw
    const int base_b = blockIdx.x * ROWS;

    const float* kp = dir ? bwk  : fwk;
    const float* rp = dir ? bwrk : fwrk;
    const float* bp = dir ? bwb  : fwb;
    float* buf = dir ? buf_bw : buf_fw;

    const int q  = lane >> 4;           // k-group 0..3
    const int cl = lane & 15;           // A-row / B-col within tile
    const int uu = (wv << 4) + cl;      // unit 0..127 owned by this lane

    const int sr = tid >> 5;            // staging row 0..15
    const int sc = (tid & 31) << 2;     // staging col 0..124

    // layer 0: input x, no Wk_lo correction (zero-mean input -> incoherent err)
    run_layer<false>(kp, rp, bp, x, buf, A, WKLO, dir, base_b,
                     tid, q, cl, uu, sr, sc);
    // layer 1: input = layer-0 h sequence (nonzero mean -> keep Wk_lo), in-place
    run_layer<true>(kp + ND * NG, rp + NU * NG, bp + NG, buf, buf, A, WKLO,
                    dir, base_b, tid, q, cl, uu, sr, sc);
}

// ---- merge: out = 0.5*(fw + bw) ---------------------------------------------
__global__ void merge_out(const float* __restrict__ a, const float* __restrict__ b,
                          float* __restrict__ o, int nvec) {
    int i = blockIdx.x * blockDim.x + threadIdx.x;
    const int st = gridDim.x * blockDim.x;
    for (; i < nvec; i += st) {
        const float4 va = ((const float4*)a)[i];
        const float4 vb = ((const float4*)b)[i];
        float4 r;
        r.x = 0.5f * (va.x + vb.x);
        r.y = 0.5f * (va.y + vb.y);
        r.z = 0.5f * (va.z + vb.z);
        r.w = 0.5f * (va.w + vb.w);
        ((float4*)o)[i] = r;
    }
}

extern "C" void kernel_launch(void* const* d_in, const int* in_sizes, int n_in,
                              void* d_out, int out_size, void* d_ws, size_t ws_size,
                              hipStream_t stream) {
    const float* x    = (const float*)d_in[0];
    const float* fwk  = (const float*)d_in[1];
    const float* fwrk = (const float*)d_in[2];
    const float* fwb  = (const float*)d_in[3];
    const float* bwk  = (const float*)d_in[4];
    const float* bwrk = (const float*)d_in[5];
    const float* bwb  = (const float*)d_in[6];
    float* out = (float*)d_out;

    const size_t seq = (size_t)NB * NT * NU;     // 26,214,400 elements
    float* buf_fw = (float*)d_ws;                // fw h-sequence fp32 (l0 then l1 in-place)
    float* buf_bw = buf_fw + seq;                // bw h-sequence fp32

    const size_t lds_bytes = (size_t)(LDS_A_ELEMS + LDS_WK_ELEMS) * sizeof(u16); // 147456
    (void)hipFuncSetAttribute((const void*)lstm_scan,
                              hipFuncAttributeMaxDynamicSharedMemorySize,
                              (int)lds_bytes);

    lstm_scan<<<dim3(NB / ROWS, 2), 512, lds_bytes, stream>>>(
        x, fwk, fwrk, fwb, bwk, bwrk, bwb, buf_fw, buf_bw);

    const int nvec = (int)(seq / 4);
    merge_out<<<2048, 256, 0, stream>>>(buf_fw, buf_bw, out, nvec);
}